// Round 2
// baseline (451.248 us; speedup 1.0000x reference)
//
#include <hip/hip_runtime.h>
#include <math.h>

#define NPATH 70656
#define NBATCH 512
#define OUTD 480
#define OUTSZ (OUTD*OUTD)   // 230400 per point

// c-region start offset per pair p = lo*3+li (path order: lo outer, li inner)
// sizes: 16384,8192,4096 | 8192,12288,6144 | 4096,6144,5120
constexpr int CBEG_TAB[9] = {0,16384,24576,28672,36864,49152,55296,59392,65536};

// ---------------- Kernel A: spherical harmonics + hT ----------------
__global__ __launch_bounds__(256) void sh_mlp_kernel(
    const float* __restrict__ r, const float* __restrict__ w1,
    const float* __restrict__ b1, float* __restrict__ Yg,
    float* __restrict__ hT)
{
  int z = blockIdx.x*256 + threadIdx.x;
  if (z >= NBATCH) return;
  float x = r[3*z], y = r[3*z+1], zz = r[3*z+2];
  float nrm = sqrtf(x*x + y*y + zz*zz);
  float inv = 1.0f / fmaxf(nrm, 1e-9f);
  float dx = x*inv, dy = y*inv, dz = zz*inv;
  float rxy = sqrtf(fmaxf(dx*dx + dy*dy, 1e-18f));
  float cphi = dx/rxy, sphi = dy/rxy;
  float somx2 = sqrtf(fmaxf(1.0f - dz*dz, 1e-12f));

  float P[5][5];
  float pmm = 1.0f;
  #pragma unroll
  for (int m = 0; m < 5; ++m) {
    if (m > 0) pmm *= (float)(2*m-1) * somx2;
    P[m][m] = pmm;
    if (m+1 < 5) P[m+1][m] = dz * (float)(2*m+1) * pmm;
    #pragma unroll
    for (int l = m+2; l < 5; ++l)
      P[l][m] = ((float)(2*l-1)*dz*P[l-1][m] - (float)(l+m-1)*P[l-2][m]) / (float)(l-m);
  }
  float cm[5], sm[5];
  cm[0]=1.0f; sm[0]=0.0f; cm[1]=cphi; sm[1]=sphi;
  #pragma unroll
  for (int m = 2; m < 5; ++m) {
    cm[m] = cm[m-1]*cphi - sm[m-1]*sphi;
    sm[m] = sm[m-1]*cphi + cm[m-1]*sphi;
  }
  const float fact[9] = {1,1,2,6,24,120,720,5040,40320};
  int row = 0;
  #pragma unroll
  for (int l = 0; l < 5; ++l) {
    #pragma unroll
    for (int m = -l; m <= l; ++m) {
      int am = m < 0 ? -m : m;
      float N = sqrtf((float)(2*l+1) / 12.566370614359172f * fact[l-am] / fact[l+am]);
      float v;
      if (m == 0)      v = N * P[l][0];
      else if (m > 0)  v = 1.4142135623730951f * N * P[l][am] * cm[am];
      else             v = 1.4142135623730951f * N * P[l][am] * sm[am];
      Yg[z*25 + row] = v;
      ++row;
    }
  }
  #pragma unroll
  for (int k = 0; k < 64; ++k)
    hT[k*NBATCH + z] = fmaxf(nrm * w1[k] + b1[k], 0.0f);
}

// ---------------- Kernel B: coefficients = h @ w2 + b2 ----------------
// one thread per path column; w2 column held in 64 VGPRs (w2 read once from HBM);
// hT reads are wave-uniform -> scalar loads; 16 z accumulators per pass.
__global__ __launch_bounds__(256) void coeff_kernel(
    const float* __restrict__ hT, const float* __restrict__ w2,
    const float* __restrict__ b2, float* __restrict__ C,
    int z0, int nz)
{
  int p = blockIdx.x*256 + threadIdx.x;
  float w2c[64];
  #pragma unroll
  for (int k = 0; k < 64; ++k) w2c[k] = w2[(size_t)k*NPATH + p];
  float b2p = b2[p];
  for (int zb = 0; zb < nz; zb += 16) {
    float acc[16];
    #pragma unroll
    for (int t = 0; t < 16; ++t) acc[t] = b2p;
    #pragma unroll
    for (int k = 0; k < 64; ++k) {
      const float* hrow = hT + k*NBATCH + z0 + zb;   // wave-uniform address
      float w = w2c[k];
      #pragma unroll
      for (int t = 0; t < 16; ++t) acc[t] = fmaf(hrow[t], w, acc[t]);
    }
    #pragma unroll
    for (int t = 0; t < 16; ++t)
      C[(size_t)(zb + t)*NPATH + p] = acc[t];
  }
}

// ---------------- Kernel C: tensor-product expansion (one instantiation per pair) ----------------
template<int LO, int LI>
__global__ __launch_bounds__(256) void tp_kernel(
    const float* __restrict__ Yg, const float* __restrict__ C,
    const float* __restrict__ Q, float* __restrict__ out, int z0)
{
  constexpr int DI = 2*LO+1, DJ = 2*LI+1;
  constexpr int MI = 128>>LI;
  constexpr int NL = 2*((LO<LI)?LO:LI)+1;
  constexpr int LF0 = (LO>LI)?(LO-LI):(LI-LO);
  constexpr int QDIM = (LO+LI+1)*(LO+LI+1) - LF0*LF0;  // sum of (2lf+1) over filters
  constexpr int W = MI*DJ;                              // region width (cols)
  constexpr int ROWOFF = (LO==0)?0:((LO==1)?128:320);
  constexpr int COLOFF = (LI==0)?0:((LI==1)?128:320);
  constexpr int CBEG = CBEG_TAB[LO*3+LI];
  constexpr int ASIZE = DI*DJ*NL;                       // <= 125
  constexpr float NS = (LO==0)?224.0f:((LO==1)?416.0f:480.0f);

  __shared__ float Yz[25];
  __shared__ float A[ASIZE];
  const int tid = threadIdx.x;
  const int zrel = blockIdx.y;
  const int z = z0 + zrel;
  if (tid < 25) Yz[tid] = Yg[z*25 + tid];
  __syncthreads();
  if (tid < ASIZE) {
    int i   = tid / (DJ*NL);
    int rem = tid % (DJ*NL);
    int j   = rem / NL;
    int kf  = rem % NL;
    int lf  = LF0 + kf;
    const float* qq = Q + (i*DJ + j)*QDIM + kf*(2*LF0 + kf);  // offset within filter dim
    float s = 0.0f;
    for (int m = 0; m < 2*lf+1; ++m) s += qq[m] * Yz[lf*lf + m];
    A[tid] = s;
  }
  __syncthreads();

  const float xn = sqrtf((float)(2*LI+1) * 12.566370614359172f / NS);
  const float* Cz = C + (size_t)zrel*NPATH + CBEG;
  float* oz = out + (size_t)z*OUTSZ;
  int f0 = blockIdx.x*1024 + tid;
  #pragma unroll
  for (int it = 0; it < 4; ++it) {
    int f = f0 + it*256;
    int rr = f / W,  cc = f - rr*W;
    int u  = rr / DI, i = rr - u*DI;
    int v  = cc / DJ, j = cc - v*DJ;
    const float* cp = Cz + (u*MI + v)*NL;
    const float* ap = A  + (i*DJ + j)*NL;
    float s = 0.0f;
    #pragma unroll
    for (int k = 0; k < NL; ++k) s += ap[k]*cp[k];
    oz[(ROWOFF + rr)*OUTD + (COLOFF + cc)] = s*xn;
  }
}

extern "C" void kernel_launch(void* const* d_in, const int* in_sizes, int n_in,
                              void* d_out, int out_size, void* d_ws, size_t ws_size,
                              hipStream_t stream)
{
  (void)in_sizes; (void)n_in; (void)out_size;
  const float* r  = (const float*)d_in[0];
  const float* w1 = (const float*)d_in[1];
  const float* b1 = (const float*)d_in[2];
  const float* w2 = (const float*)d_in[3];
  const float* b2 = (const float*)d_in[4];
  float* out = (float*)d_out;

  float* ws = (float*)d_ws;
  float* Yg = ws;                       // 512*25   = 12800 floats
  float* hT = ws + 12800;               // 64*512   = 32768 floats
  float* Cb = ws + 12800 + 32768;       // slab*NPATH floats

  // pick largest power-of-2 z-slab whose c-buffer fits the workspace
  size_t cap_floats = ws_size / 4;
  size_t avail = cap_floats > 45568 ? cap_floats - 45568 : 0;
  int slab = 512;
  while (slab > 16 && (size_t)slab * NPATH > avail) slab >>= 1;

  hipLaunchKernelGGL(sh_mlp_kernel, dim3(2), dim3(256), 0, stream, r, w1, b1, Yg, hT);

#define LAUNCH_TP(LOv, LIv) do {                                                   \
    constexpr int H_ = (128>>LOv)*(2*LOv+1);                                       \
    constexpr int W_ = (128>>LIv)*(2*LIv+1);                                       \
    hipLaunchKernelGGL((tp_kernel<LOv,LIv>), dim3((H_*W_)/1024, slab), dim3(256),  \
                       0, stream, Yg, Cb,                                          \
                       (const float*)d_in[5 + LOv*3 + LIv], out, z0);              \
  } while (0)

  for (int z0 = 0; z0 < NBATCH; z0 += slab) {
    hipLaunchKernelGGL(coeff_kernel, dim3(276), dim3(256), 0, stream,
                       hT, w2, b2, Cb, z0, slab);
    LAUNCH_TP(0,0); LAUNCH_TP(0,1); LAUNCH_TP(0,2);
    LAUNCH_TP(1,0); LAUNCH_TP(1,1); LAUNCH_TP(1,2);
    LAUNCH_TP(2,0); LAUNCH_TP(2,1); LAUNCH_TP(2,2);
  }
#undef LAUNCH_TP
}

// Round 3
// 318.280 us; speedup vs baseline: 1.4178x; 1.4178x over previous
//
#include <hip/hip_runtime.h>
#include <math.h>

#define NPATH 70656
#define NBATCH 512
#define OUTD 480
#define OUTSZ (OUTD*OUTD)   // 230400 per point

// c-region start offset per pair p = lo*3+li (path order: lo outer, li inner)
// sizes: 16384,8192,4096 | 8192,12288,6144 | 4096,6144,5120
constexpr int CBEG_TAB[9] = {0,16384,24576,28672,36864,49152,55296,59392,65536};

// ---------------- Kernel A: spherical harmonics + hT ----------------
__global__ __launch_bounds__(256) void sh_mlp_kernel(
    const float* __restrict__ r, const float* __restrict__ w1,
    const float* __restrict__ b1, float* __restrict__ Yg,
    float* __restrict__ hT)
{
  int z = blockIdx.x*256 + threadIdx.x;
  if (z >= NBATCH) return;
  float x = r[3*z], y = r[3*z+1], zz = r[3*z+2];
  float nrm = sqrtf(x*x + y*y + zz*zz);
  float inv = 1.0f / fmaxf(nrm, 1e-9f);
  float dx = x*inv, dy = y*inv, dz = zz*inv;
  float rxy = sqrtf(fmaxf(dx*dx + dy*dy, 1e-18f));
  float cphi = dx/rxy, sphi = dy/rxy;
  float somx2 = sqrtf(fmaxf(1.0f - dz*dz, 1e-12f));

  float P[5][5];
  float pmm = 1.0f;
  #pragma unroll
  for (int m = 0; m < 5; ++m) {
    if (m > 0) pmm *= (float)(2*m-1) * somx2;
    P[m][m] = pmm;
    if (m+1 < 5) P[m+1][m] = dz * (float)(2*m+1) * pmm;
    #pragma unroll
    for (int l = m+2; l < 5; ++l)
      P[l][m] = ((float)(2*l-1)*dz*P[l-1][m] - (float)(l+m-1)*P[l-2][m]) / (float)(l-m);
  }
  float cm[5], sm[5];
  cm[0]=1.0f; sm[0]=0.0f; cm[1]=cphi; sm[1]=sphi;
  #pragma unroll
  for (int m = 2; m < 5; ++m) {
    cm[m] = cm[m-1]*cphi - sm[m-1]*sphi;
    sm[m] = sm[m-1]*cphi + cm[m-1]*sphi;
  }
  const float fact[9] = {1,1,2,6,24,120,720,5040,40320};
  int row = 0;
  #pragma unroll
  for (int l = 0; l < 5; ++l) {
    #pragma unroll
    for (int m = -l; m <= l; ++m) {
      int am = m < 0 ? -m : m;
      float N = sqrtf((float)(2*l+1) / 12.566370614359172f * fact[l-am] / fact[l+am]);
      float v;
      if (m == 0)      v = N * P[l][0];
      else if (m > 0)  v = 1.4142135623730951f * N * P[l][am] * cm[am];
      else             v = 1.4142135623730951f * N * P[l][am] * sm[am];
      Yg[z*25 + row] = v;
      ++row;
    }
  }
  #pragma unroll
  for (int k = 0; k < 64; ++k)
    hT[k*NBATCH + z] = fmaxf(nrm * w1[k] + b1[k], 0.0f);
}

// ---------------- Kernel B: coefficients = h @ w2 + b2 ----------------
// one thread per (path column, z-chunk); w2 column in 64 VGPRs;
// hT reads wave-uniform -> s_load; blockIdx.y z-chunks restore occupancy
// (was 1.08 waves/SIMD -> scalar-load latency exposed; now ~4.3).
__global__ __launch_bounds__(256) void coeff_kernel(
    const float* __restrict__ hT, const float* __restrict__ w2,
    const float* __restrict__ b2, float* __restrict__ C,
    int z0, int zch)
{
  int p = blockIdx.x*256 + threadIdx.x;
  int zc = blockIdx.y * zch;            // relative to slab start
  float w2c[64];
  #pragma unroll
  for (int k = 0; k < 64; ++k) w2c[k] = w2[(size_t)k*NPATH + p];
  float b2p = b2[p];
  for (int zb = 0; zb < zch; zb += 16) {
    float acc[16];
    #pragma unroll
    for (int t = 0; t < 16; ++t) acc[t] = b2p;
    #pragma unroll
    for (int k = 0; k < 64; ++k) {
      const float* hrow = hT + k*NBATCH + z0 + zc + zb;   // wave-uniform address
      float w = w2c[k];
      #pragma unroll
      for (int t = 0; t < 16; ++t) acc[t] = fmaf(hrow[t], w, acc[t]);
    }
    #pragma unroll
    for (int t = 0; t < 16; ++t)
      C[(size_t)(zc + zb + t)*NPATH + p] = acc[t];
  }
}

// ---------------- Kernel C: tensor-product expansion ----------------
// 2 z per block: the 3 integer divisions per output element are computed
// once and reused for both z; A for both z lives in LDS (2*ASIZE <= 250).
template<int LO, int LI>
__global__ __launch_bounds__(256) void tp_kernel(
    const float* __restrict__ Yg, const float* __restrict__ C,
    const float* __restrict__ Q, float* __restrict__ out, int z0)
{
  constexpr int DI = 2*LO+1, DJ = 2*LI+1;
  constexpr int MI = 128>>LI;
  constexpr int NL = 2*((LO<LI)?LO:LI)+1;
  constexpr int LF0 = (LO>LI)?(LO-LI):(LI-LO);
  constexpr int QDIM = (LO+LI+1)*(LO+LI+1) - LF0*LF0;  // sum of (2lf+1) over filters
  constexpr int W = MI*DJ;                              // region width (cols)
  constexpr int ROWOFF = (LO==0)?0:((LO==1)?128:320);
  constexpr int COLOFF = (LI==0)?0:((LI==1)?128:320);
  constexpr int CBEG = CBEG_TAB[LO*3+LI];
  constexpr int ASIZE = DI*DJ*NL;                       // <= 125
  constexpr float NS = (LO==0)?224.0f:((LO==1)?416.0f:480.0f);

  __shared__ float Yz[2][25];
  __shared__ float A[2][ASIZE];
  const int tid = threadIdx.x;
  const int zp = blockIdx.y;            // z-pair index within slab
  const int z = z0 + 2*zp;              // absolute z of first of the pair
  if (tid < 50) Yz[tid/25][tid%25] = Yg[(z + tid/25)*25 + tid%25];
  __syncthreads();
  if (tid < 2*ASIZE) {
    int zz  = tid / ASIZE;
    int t   = tid % ASIZE;
    int i   = t / (DJ*NL);
    int rem = t % (DJ*NL);
    int j   = rem / NL;
    int kf  = rem % NL;
    int lf  = LF0 + kf;
    const float* qq = Q + (i*DJ + j)*QDIM + kf*(2*LF0 + kf);  // offset within filter dim
    float s = 0.0f;
    for (int m = 0; m < 2*lf+1; ++m) s += qq[m] * Yz[zz][lf*lf + m];
    A[zz][t] = s;
  }
  __syncthreads();

  const float xn = sqrtf((float)(2*LI+1) * 12.566370614359172f / NS);
  const float* Cz0 = C + (size_t)(2*zp)*NPATH + CBEG;
  float* oz0 = out + (size_t)z*OUTSZ + ROWOFF*OUTD + COLOFF;
  int f0 = blockIdx.x*1024 + tid;
  #pragma unroll
  for (int it = 0; it < 4; ++it) {
    int f = f0 + it*256;
    int rr = f / W,  cc = f - rr*W;
    int u  = rr / DI, i = rr - u*DI;
    int v  = cc / DJ, j = cc - v*DJ;
    int cidx = (u*MI + v)*NL;
    int aidx = (i*DJ + j)*NL;
    int oidx = rr*OUTD + cc;
    #pragma unroll
    for (int zz = 0; zz < 2; ++zz) {
      const float* cp = Cz0 + (size_t)zz*NPATH + cidx;
      float s = 0.0f;
      #pragma unroll
      for (int k = 0; k < NL; ++k) s += A[zz][aidx + k]*cp[k];
      oz0[(size_t)zz*OUTSZ + oidx] = s*xn;
    }
  }
}

extern "C" void kernel_launch(void* const* d_in, const int* in_sizes, int n_in,
                              void* d_out, int out_size, void* d_ws, size_t ws_size,
                              hipStream_t stream)
{
  (void)in_sizes; (void)n_in; (void)out_size;
  const float* r  = (const float*)d_in[0];
  const float* w1 = (const float*)d_in[1];
  const float* b1 = (const float*)d_in[2];
  const float* w2 = (const float*)d_in[3];
  const float* b2 = (const float*)d_in[4];
  float* out = (float*)d_out;

  float* ws = (float*)d_ws;
  float* Yg = ws;                       // 512*25   = 12800 floats
  float* hT = ws + 12800;               // 64*512   = 32768 floats
  float* Cb = ws + 12800 + 32768;       // slab*NPATH floats

  // pick largest power-of-2 z-slab whose c-buffer fits the workspace
  size_t cap_floats = ws_size / 4;
  size_t avail = cap_floats > 45568 ? cap_floats - 45568 : 0;
  int slab = 512;
  while (slab > 16 && (size_t)slab * NPATH > avail) slab >>= 1;
  int zch = slab < 128 ? slab : 128;    // z-chunk per coeff block row

  hipLaunchKernelGGL(sh_mlp_kernel, dim3(2), dim3(256), 0, stream, r, w1, b1, Yg, hT);

#define LAUNCH_TP(LOv, LIv) do {                                                   \
    constexpr int H_ = (128>>LOv)*(2*LOv+1);                                       \
    constexpr int W_ = (128>>LIv)*(2*LIv+1);                                       \
    hipLaunchKernelGGL((tp_kernel<LOv,LIv>), dim3((H_*W_)/1024, slab/2), dim3(256),\
                       0, stream, Yg, Cb,                                          \
                       (const float*)d_in[5 + LOv*3 + LIv], out, z0);              \
  } while (0)

  for (int z0 = 0; z0 < NBATCH; z0 += slab) {
    hipLaunchKernelGGL(coeff_kernel, dim3(276, slab/zch), dim3(256), 0, stream,
                       hT, w2, b2, Cb, z0, zch);
    LAUNCH_TP(0,0); LAUNCH_TP(0,1); LAUNCH_TP(0,2);
    LAUNCH_TP(1,0); LAUNCH_TP(1,1); LAUNCH_TP(1,2);
    LAUNCH_TP(2,0); LAUNCH_TP(2,1); LAUNCH_TP(2,2);
  }
#undef LAUNCH_TP
}